// Round 1
// baseline (86.815 us; speedup 1.0000x reference)
//
#include <hip/hip_runtime.h>

#define NN 4096
#define FIN 256
#define FOUT 64
#define NH 4
#define CAP 1024

// Kernel 1: h_prime[h,n,:] = h[n,:] @ w[h,:,:]; src[h,n] = h_prime . a_src[h]; dst likewise.
// One wave (64 threads) per (head, node); lane o computes output feature o.
__global__ __launch_bounds__(64) void gat_hprime(
    const float* __restrict__ h, const float* __restrict__ w,
    const float* __restrict__ a_src, const float* __restrict__ a_dst,
    float* __restrict__ h_prime, float* __restrict__ src, float* __restrict__ dst)
{
    const int blk  = blockIdx.x;      // head * NN + n
    const int head = blk >> 12;
    const int n    = blk & (NN - 1);
    const int o    = threadIdx.x;     // 0..63

    __shared__ float hrow[FIN];
    for (int f = o; f < FIN; f += 64) hrow[f] = h[n * FIN + f];
    __syncthreads();

    const float* wp = w + head * FIN * FOUT + o;   // stride FOUT over f, coalesced over o
    float acc = 0.f;
#pragma unroll 8
    for (int f = 0; f < FIN; ++f)
        acc = fmaf(hrow[f], wp[f * FOUT], acc);

    h_prime[(head * NN + n) * FOUT + o] = acc;

    float vs = acc * a_src[head * FOUT + o];
    float vd = acc * a_dst[head * FOUT + o];
#pragma unroll
    for (int off = 32; off >= 1; off >>= 1) {
        vs += __shfl_xor(vs, off, 64);
        vd += __shfl_xor(vd, off, 64);
    }
    if (o == 0) {
        src[head * NN + n] = vs;
        dst[head * NN + n] = vd;
    }
}

// Kernel 2: per row i — scan adj row once, build edge list, softmax per head, gather h_prime.
__global__ __launch_bounds__(256) void gat_attn(
    const int* __restrict__ adj,
    const float* __restrict__ h_prime, const float* __restrict__ src,
    const float* __restrict__ dst, const float* __restrict__ bias,
    float* __restrict__ out)
{
    const int i = blockIdx.x;
    const int t = threadIdx.x;

    __shared__ int   idx_l[CAP];
    __shared__ float sc[NH][CAP];
    __shared__ int   cnt;
    __shared__ float inv_sum[NH];

    if (t == 0) cnt = 0;
    __syncthreads();

    float s_i[NH];
#pragma unroll
    for (int hh = 0; hh < NH; ++hh) s_i[hh] = src[hh * NN + i];

    const int* arow = adj + (size_t)i * NN;
    for (int j = t; j < NN; j += 256) {
        if (arow[j] != 0) {
            int p = atomicAdd(&cnt, 1);
            if (p < CAP) {
                idx_l[p] = j;
#pragma unroll
                for (int hh = 0; hh < NH; ++hh) {
                    float s = s_i[hh] + dst[hh * NN + j];
                    sc[hh][p] = (s >= 0.f) ? s : 0.2f * s;   // leaky_relu(0.2)
                }
            }
        }
    }
    __syncthreads();
    const int count = min(cnt, CAP);

    const int wave = t >> 6, lane = t & 63;
    {
        // wave w handles head w: stable softmax over the edge list
        const int hh = wave;
        float m = -3.4e38f;
        for (int p = lane; p < count; p += 64) m = fmaxf(m, sc[hh][p]);
#pragma unroll
        for (int off = 32; off >= 1; off >>= 1) m = fmaxf(m, __shfl_xor(m, off, 64));
        float e = 0.f;
        for (int p = lane; p < count; p += 64) {
            float v = __expf(sc[hh][p] - m);
            sc[hh][p] = v;
            e += v;
        }
#pragma unroll
        for (int off = 32; off >= 1; off >>= 1) e += __shfl_xor(e, off, 64);
        if (lane == 0) inv_sum[hh] = 1.f / e;
    }
    __syncthreads();

    // thread (hh = t/64, o = t&63): weighted gather of h_prime rows
    const int hh = wave;
    const int o  = lane;
    float acc = 0.f;
    for (int p = 0; p < count; ++p) {
        const int j = idx_l[p];
        acc = fmaf(sc[hh][p], h_prime[(hh * NN + j) * FOUT + o], acc);
    }
    out[i * (NH * FOUT) + hh * FOUT + o] = acc * inv_sum[hh] + bias[o];
}

extern "C" void kernel_launch(void* const* d_in, const int* in_sizes, int n_in,
                              void* d_out, int out_size, void* d_ws, size_t ws_size,
                              hipStream_t stream) {
    const float* h     = (const float*)d_in[0];
    const int*   adj   = (const int*)d_in[1];
    const float* w     = (const float*)d_in[2];
    const float* a_src = (const float*)d_in[3];
    const float* a_dst = (const float*)d_in[4];
    const float* bias  = (const float*)d_in[5];
    float* out = (float*)d_out;

    float* wsf     = (float*)d_ws;
    float* h_prime = wsf;                       // NH*NN*FOUT = 1,048,576 floats
    float* src     = h_prime + NH * NN * FOUT;  // NH*NN
    float* dst     = src + NH * NN;             // NH*NN

    gat_hprime<<<NH * NN, 64, 0, stream>>>(h, w, a_src, a_dst, h_prime, src, dst);
    gat_attn<<<NN, 256, 0, stream>>>(adj, h_prime, src, dst, bias, out);
}

// Round 2
// 79.034 us; speedup vs baseline: 1.0985x; 1.0985x over previous
//
#include <hip/hip_runtime.h>

#define NN 4096
#define FIN 256
#define FOUT 64
#define NH 4
#define CAP 128   // max edges/row; Binomial(4096,0.01) mean 42, P(>127) ~ 1e-30
#define NT 16     // nodes per wave in hprime

// ---------------------------------------------------------------------------
// Kernel 1: h_prime[h,n,:] = h[n,:] @ w[h,:,:]; src/dst logits; zero counts.
// 1024 blocks x 64 threads: block = (head, 16-node tile). Lane o = out feature.
// w traffic amortized 16x vs one-node-per-wave.
// ---------------------------------------------------------------------------
__global__ __launch_bounds__(64) void gat_hprime(
    const float* __restrict__ h, const float* __restrict__ w,
    const float* __restrict__ a_src, const float* __restrict__ a_dst,
    float* __restrict__ h_prime, float* __restrict__ src, float* __restrict__ dst,
    int* __restrict__ counts)
{
    const int blk  = blockIdx.x;          // 0..1023
    const int head = blk >> 8;            // 0..3
    const int n0   = (blk & 255) * NT;    // node tile base
    const int o    = threadIdx.x;         // 0..63

    // zero the CSR counters (65536 threads >= 4096 rows)
    const int gid = blk * 64 + o;
    if (gid < NN) counts[gid] = 0;

    __shared__ float hs[NT * FIN];        // 16 KB, contiguous rows
    const float4* hsrc = (const float4*)(h + (size_t)n0 * FIN);
    for (int idx = o; idx < NT * FIN / 4; idx += 64)
        ((float4*)hs)[idx] = hsrc[idx];
    __syncthreads();

    const float* wp = w + head * FIN * FOUT + o;  // coalesced over o
    float acc[NT];
#pragma unroll
    for (int t = 0; t < NT; ++t) acc[t] = 0.f;

    for (int f = 0; f < FIN; f += 4) {
        const float w0 = wp[(f + 0) * FOUT];
        const float w1 = wp[(f + 1) * FOUT];
        const float w2 = wp[(f + 2) * FOUT];
        const float w3 = wp[(f + 3) * FOUT];
#pragma unroll
        for (int t = 0; t < NT; ++t) {
            float4 hv = *(const float4*)&hs[t * FIN + f];  // wave-broadcast b128
            acc[t] = fmaf(hv.x, w0, acc[t]);
            acc[t] = fmaf(hv.y, w1, acc[t]);
            acc[t] = fmaf(hv.z, w2, acc[t]);
            acc[t] = fmaf(hv.w, w3, acc[t]);
        }
    }

    const float as = a_src[head * FOUT + o];
    const float ad = a_dst[head * FOUT + o];
#pragma unroll
    for (int t = 0; t < NT; ++t) {
        h_prime[(size_t)(head * NN + n0 + t) * FOUT + o] = acc[t];
        float vs = acc[t] * as;
        float vd = acc[t] * ad;
#pragma unroll
        for (int off = 32; off >= 1; off >>= 1) {
            vs += __shfl_xor(vs, off, 64);
            vd += __shfl_xor(vd, off, 64);
        }
        if (o == 0) {
            src[head * NN + n0 + t] = vs;
            dst[head * NN + n0 + t] = vd;
        }
    }
}

// ---------------------------------------------------------------------------
// Kernel 2: BW-bound adjacency scan -> fixed-CAP CSR.
// Grid-stride int4 loads; wave-level prefix compaction; 1 atomic per wave.
// A wave's 64 lanes cover 256 consecutive ints -> single row (4096-aligned).
// ---------------------------------------------------------------------------
__global__ __launch_bounds__(256) void gat_scan(
    const int* __restrict__ adj, int* __restrict__ counts, int* __restrict__ edges)
{
    const int lane  = threadIdx.x & 63;
    const int nvec  = NN * NN / 4;                 // 4,194,304 int4
    const int step  = gridDim.x * 256;
    for (int v = blockIdx.x * 256 + threadIdx.x; v < nvec; v += step) {
        const int4 a  = ((const int4*)adj)[v];
        const int  j0 = v * 4;
        const int  row = j0 >> 12;                 // wave-uniform
        const int  c = (a.x != 0) + (a.y != 0) + (a.z != 0) + (a.w != 0);

        // inclusive prefix sum over the wave
        int pre = c;
#pragma unroll
        for (int off = 1; off < 64; off <<= 1) {
            int nb = __shfl_up(pre, off, 64);
            if (lane >= off) pre += nb;
        }
        const int tot = __shfl(pre, 63, 64);
        int basev = 0;
        if (lane == 63 && tot > 0) basev = atomicAdd(&counts[row], tot);
        basev = __shfl(basev, 63, 64);

        int wpos = basev + pre - c;
        const int col0 = j0 & (NN - 1);
        int* erow = edges + (size_t)row * CAP;
        if (a.x) { if (wpos < CAP) erow[wpos] = col0 + 0; ++wpos; }
        if (a.y) { if (wpos < CAP) erow[wpos] = col0 + 1; ++wpos; }
        if (a.z) { if (wpos < CAP) erow[wpos] = col0 + 2; ++wpos; }
        if (a.w) { if (wpos < CAP) erow[wpos] = col0 + 3; ++wpos; }
    }
}

// ---------------------------------------------------------------------------
// Kernel 3: per-row softmax + gather from CSR. Block = row, wave = head.
// ---------------------------------------------------------------------------
__global__ __launch_bounds__(256) void gat_attn(
    const int* __restrict__ counts, const int* __restrict__ edges,
    const float* __restrict__ h_prime, const float* __restrict__ src,
    const float* __restrict__ dst, const float* __restrict__ bias,
    float* __restrict__ out)
{
    const int i    = blockIdx.x;
    const int t    = threadIdx.x;
    const int wave = t >> 6, lane = t & 63;

    __shared__ int   idx_l[CAP];
    __shared__ float sc[NH][CAP];
    __shared__ float inv_sum[NH];

    const int count = min(counts[i], CAP);

    // scores: thread p handles edge p (count <= 128 < 256)
    if (t < count) {
        const int j = edges[(size_t)i * CAP + t];
        idx_l[t] = j;
#pragma unroll
        for (int hh = 0; hh < NH; ++hh) {
            float s = src[hh * NN + i] + dst[hh * NN + j];
            sc[hh][t] = (s >= 0.f) ? s : 0.2f * s;   // leaky_relu(0.2)
        }
    }
    __syncthreads();

    // per-head softmax (wave hh)
    {
        const int hh = wave;
        float m = -3.4e38f;
        for (int p = lane; p < count; p += 64) m = fmaxf(m, sc[hh][p]);
#pragma unroll
        for (int off = 32; off >= 1; off >>= 1) m = fmaxf(m, __shfl_xor(m, off, 64));
        float e = 0.f;
        for (int p = lane; p < count; p += 64) {
            float v = __expf(sc[hh][p] - m);
            sc[hh][p] = v;
            e += v;
        }
#pragma unroll
        for (int off = 32; off >= 1; off >>= 1) e += __shfl_xor(e, off, 64);
        if (lane == 0) inv_sum[hh] = 1.f / e;
    }
    __syncthreads();

    // gather: thread (wave=head, lane=feature)
    float acc = 0.f;
    const float* hp = h_prime + (size_t)(wave * NN) * FOUT + lane;
    for (int p = 0; p < count; ++p)
        acc = fmaf(sc[wave][p], hp[(size_t)idx_l[p] * FOUT], acc);
    out[(size_t)i * (NH * FOUT) + wave * FOUT + lane] = acc * inv_sum[wave] + bias[lane];
}

extern "C" void kernel_launch(void* const* d_in, const int* in_sizes, int n_in,
                              void* d_out, int out_size, void* d_ws, size_t ws_size,
                              hipStream_t stream) {
    const float* h     = (const float*)d_in[0];
    const int*   adj   = (const int*)d_in[1];
    const float* w     = (const float*)d_in[2];
    const float* a_src = (const float*)d_in[3];
    const float* a_dst = (const float*)d_in[4];
    const float* bias  = (const float*)d_in[5];
    float* out = (float*)d_out;

    float* wsf     = (float*)d_ws;
    float* h_prime = wsf;                        // NH*NN*FOUT floats = 4 MB
    float* src     = h_prime + NH * NN * FOUT;   // NH*NN
    float* dst     = src + NH * NN;              // NH*NN
    int*   counts  = (int*)(dst + NH * NN);      // NN ints
    int*   edges   = counts + NN;                // NN*CAP ints = 2 MB

    gat_hprime<<<NH * (NN / NT), 64, 0, stream>>>(h, w, a_src, a_dst,
                                                  h_prime, src, dst, counts);
    gat_scan<<<2048, 256, 0, stream>>>(adj, counts, edges);
    gat_attn<<<NN, 256, 0, stream>>>(counts, edges, h_prime, src, dst, bias, out);
}

// Round 3
// 48.243 us; speedup vs baseline: 1.7995x; 1.6382x over previous
//
#include <hip/hip_runtime.h>

#define NN 4096
#define FIN 256
#define FOUT 64
#define NH 4
#define CAP 128    // max edges/row; Binomial(4096,0.01) mean 42, P(>127) ~ 1e-30
#define HPB 512    // hprime blocks: 8 nodes x 4 heads each
#define SCB 1024   // scan blocks: 4 rows each (one wave per row)

// ---------------------------------------------------------------------------
// Stage 1 (fused, independent work split by blockIdx):
//   blocks [0, HPB):      h_prime GEMM + src/dst logits
//   blocks [HPB, +SCB):   adjacency scan -> CSR (no atomics, no pre-zero)
// ---------------------------------------------------------------------------
__global__ __launch_bounds__(256) void gat_stage1(
    const float* __restrict__ h, const int* __restrict__ adj,
    const float* __restrict__ w, const float* __restrict__ a_src,
    const float* __restrict__ a_dst,
    float* __restrict__ h_prime, float* __restrict__ src, float* __restrict__ dst,
    int* __restrict__ counts, int* __restrict__ edges)
{
    const int b    = blockIdx.x;
    const int t    = threadIdx.x;
    const int lane = t & 63;

    if (b < HPB) {
        // ---------------- h' part: 8 nodes, wave = head ----------------
        const int n0 = b * 8;
        const int hh = t >> 6;
        const int o  = lane;

        __shared__ float hs[8 * FIN];   // 8 KB
        const float4* hsrc = (const float4*)(h + (size_t)n0 * FIN);
        for (int idx = t; idx < 8 * FIN / 4; idx += 256)
            ((float4*)hs)[idx] = hsrc[idx];
        __syncthreads();

        const float* wp = w + hh * FIN * FOUT + o;   // coalesced over o
        float acc[8];
#pragma unroll
        for (int n = 0; n < 8; ++n) acc[n] = 0.f;

        for (int f = 0; f < FIN; f += 4) {
            const float w0 = wp[(f + 0) * FOUT];
            const float w1 = wp[(f + 1) * FOUT];
            const float w2 = wp[(f + 2) * FOUT];
            const float w3 = wp[(f + 3) * FOUT];
#pragma unroll
            for (int n = 0; n < 8; ++n) {
                float4 hv = *(const float4*)&hs[n * FIN + f];  // broadcast
                acc[n] = fmaf(hv.x, w0, acc[n]);
                acc[n] = fmaf(hv.y, w1, acc[n]);
                acc[n] = fmaf(hv.z, w2, acc[n]);
                acc[n] = fmaf(hv.w, w3, acc[n]);
            }
        }

        const float as = a_src[hh * FOUT + o];
        const float ad = a_dst[hh * FOUT + o];
#pragma unroll
        for (int n = 0; n < 8; ++n) {
            h_prime[(size_t)(hh * NN + n0 + n) * FOUT + o] = acc[n];
            float vs = acc[n] * as;
            float vd = acc[n] * ad;
#pragma unroll
            for (int off = 32; off >= 1; off >>= 1) {
                vs += __shfl_xor(vs, off, 64);
                vd += __shfl_xor(vd, off, 64);
            }
            if (o == 0) {
                src[hh * NN + n0 + n] = vs;
                dst[hh * NN + n0 + n] = vd;
            }
        }
    } else {
        // ---------------- scan part: one wave owns one row ----------------
        const int row = (b - HPB) * 4 + (t >> 6);
        const int4* arow = (const int4*)(adj + (size_t)row * NN);
        int* erow = edges + (size_t)row * CAP;
        int run = 0;
#pragma unroll 4
        for (int it = 0; it < NN / 4 / 64; ++it) {        // 16 iterations
            const int4 a = arow[it * 64 + lane];
            const int  c = (a.x != 0) + (a.y != 0) + (a.z != 0) + (a.w != 0);
            int pre = c;
#pragma unroll
            for (int off = 1; off < 64; off <<= 1) {
                int nb = __shfl_up(pre, off, 64);
                if (lane >= off) pre += nb;
            }
            int wpos = run + pre - c;
            const int col0 = (it * 64 + lane) * 4;
            if (a.x) { if (wpos < CAP) erow[wpos] = col0 + 0; ++wpos; }
            if (a.y) { if (wpos < CAP) erow[wpos] = col0 + 1; ++wpos; }
            if (a.z) { if (wpos < CAP) erow[wpos] = col0 + 2; ++wpos; }
            if (a.w) { if (wpos < CAP) erow[wpos] = col0 + 3; ++wpos; }
            run += __shfl(pre, 63, 64);
        }
        if (lane == 0) counts[row] = run;
    }
}

// ---------------------------------------------------------------------------
// Stage 2: per-row softmax + gather from CSR. Block = row, wave = head.
// ---------------------------------------------------------------------------
__global__ __launch_bounds__(256) void gat_attn(
    const int* __restrict__ counts, const int* __restrict__ edges,
    const float* __restrict__ h_prime, const float* __restrict__ src,
    const float* __restrict__ dst, const float* __restrict__ bias,
    float* __restrict__ out)
{
    const int i    = blockIdx.x;
    const int t    = threadIdx.x;
    const int wave = t >> 6, lane = t & 63;

    __shared__ int   idx_l[CAP];
    __shared__ float sc[NH][CAP];
    __shared__ float inv_sum[NH];

    const int count = min(counts[i], CAP);

    if (t < count) {
        const int j = edges[(size_t)i * CAP + t];
        idx_l[t] = j;
#pragma unroll
        for (int hh = 0; hh < NH; ++hh) {
            float s = src[hh * NN + i] + dst[hh * NN + j];
            sc[hh][t] = (s >= 0.f) ? s : 0.2f * s;   // leaky_relu(0.2)
        }
    }
    __syncthreads();

    {
        const int hh = wave;
        float m = -3.4e38f;
        for (int p = lane; p < count; p += 64) m = fmaxf(m, sc[hh][p]);
#pragma unroll
        for (int off = 32; off >= 1; off >>= 1) m = fmaxf(m, __shfl_xor(m, off, 64));
        float e = 0.f;
        for (int p = lane; p < count; p += 64) {
            float v = __expf(sc[hh][p] - m);
            sc[hh][p] = v;
            e += v;
        }
#pragma unroll
        for (int off = 32; off >= 1; off >>= 1) e += __shfl_xor(e, off, 64);
        if (lane == 0) inv_sum[hh] = 1.f / e;
    }
    __syncthreads();

    float acc = 0.f;
    const float* hp = h_prime + (size_t)(wave * NN) * FOUT + lane;
    for (int p = 0; p < count; ++p)
        acc = fmaf(sc[wave][p], hp[(size_t)idx_l[p] * FOUT], acc);
    out[(size_t)i * (NH * FOUT) + wave * FOUT + lane] = acc * inv_sum[wave] + bias[lane];
}

extern "C" void kernel_launch(void* const* d_in, const int* in_sizes, int n_in,
                              void* d_out, int out_size, void* d_ws, size_t ws_size,
                              hipStream_t stream) {
    const float* h     = (const float*)d_in[0];
    const int*   adj   = (const int*)d_in[1];
    const float* w     = (const float*)d_in[2];
    const float* a_src = (const float*)d_in[3];
    const float* a_dst = (const float*)d_in[4];
    const float* bias  = (const float*)d_in[5];
    float* out = (float*)d_out;

    float* wsf     = (float*)d_ws;
    float* h_prime = wsf;                        // NH*NN*FOUT floats = 4 MB
    float* src     = h_prime + NH * NN * FOUT;   // NH*NN
    float* dst     = src + NH * NN;              // NH*NN
    int*   counts  = (int*)(dst + NH * NN);      // NN ints
    int*   edges   = counts + NN;                // NN*CAP ints = 2 MB

    gat_stage1<<<HPB + SCB, 256, 0, stream>>>(h, adj, w, a_src, a_dst,
                                              h_prime, src, dst, counts, edges);
    gat_attn<<<NN, 256, 0, stream>>>(counts, edges, h_prime, src, dst, bias, out);
}

// Round 4
// 46.701 us; speedup vs baseline: 1.8590x; 1.0330x over previous
//
#include <hip/hip_runtime.h>

#define NN 4096
#define FIN 256
#define FOUT 64
#define NH 4
#define CAP 128    // max edges/row; Binomial(4096,0.01) mean 42, P(>127) ~ 1e-30
#define HPB 1024   // hprime blocks: 4 nodes x 4 heads each
#define SCB 1024   // scan blocks: 4 rows each (one wave per row)

// popcount of mask restricted to lanes strictly below mine
__device__ __forceinline__ int mbcnt64(unsigned long long m) {
    return __builtin_amdgcn_mbcnt_hi((unsigned)(m >> 32),
           __builtin_amdgcn_mbcnt_lo((unsigned)m, 0));
}

// ---------------------------------------------------------------------------
// Stage 1 (fused, independent work split by blockIdx):
//   blocks [0, HPB):      h_prime GEMM + src/dst logits (4 nodes, wave = head)
//   blocks [HPB, +SCB):   adjacency scan -> CSR via ballot+mbcnt (no shfl,
//                         no atomics, no pre-zero)
// ---------------------------------------------------------------------------
__global__ __launch_bounds__(256) void gat_stage1(
    const float* __restrict__ h, const int* __restrict__ adj,
    const float* __restrict__ w, const float* __restrict__ a_src,
    const float* __restrict__ a_dst,
    float* __restrict__ h_prime, float* __restrict__ src, float* __restrict__ dst,
    int* __restrict__ counts, int* __restrict__ edges)
{
    const int b    = blockIdx.x;
    const int t    = threadIdx.x;
    const int lane = t & 63;

    if (b < HPB) {
        // ---------------- h' part: 4 nodes, wave = head ----------------
        const int n0 = b * 4;
        const int hh = t >> 6;
        const int o  = lane;

        __shared__ float hs[4 * FIN];   // 4 KB
        if (t < 4 * FIN / 4)
            ((float4*)hs)[t] = ((const float4*)(h + (size_t)n0 * FIN))[t];
        __syncthreads();

        const float* wp = w + hh * FIN * FOUT + o;   // coalesced over o
        float acc[4] = {0.f, 0.f, 0.f, 0.f};

        for (int f = 0; f < FIN; f += 4) {
            const float w0 = wp[(f + 0) * FOUT];
            const float w1 = wp[(f + 1) * FOUT];
            const float w2 = wp[(f + 2) * FOUT];
            const float w3 = wp[(f + 3) * FOUT];
#pragma unroll
            for (int n = 0; n < 4; ++n) {
                float4 hv = *(const float4*)&hs[n * FIN + f];  // broadcast
                acc[n] = fmaf(hv.x, w0, acc[n]);
                acc[n] = fmaf(hv.y, w1, acc[n]);
                acc[n] = fmaf(hv.z, w2, acc[n]);
                acc[n] = fmaf(hv.w, w3, acc[n]);
            }
        }

        const float as = a_src[hh * FOUT + o];
        const float ad = a_dst[hh * FOUT + o];
#pragma unroll
        for (int n = 0; n < 4; ++n) {
            h_prime[(size_t)(hh * NN + n0 + n) * FOUT + o] = acc[n];
            float vs = acc[n] * as;
            float vd = acc[n] * ad;
#pragma unroll
            for (int off = 32; off >= 1; off >>= 1) {
                vs += __shfl_xor(vs, off, 64);
                vd += __shfl_xor(vd, off, 64);
            }
            if (o == 0) {
                src[hh * NN + n0 + n] = vs;
                dst[hh * NN + n0 + n] = vd;
            }
        }
    } else {
        // ---------------- scan part: one wave owns one row ----------------
        const int row = (b - HPB) * 4 + (t >> 6);
        const int4* arow = (const int4*)(adj + (size_t)row * NN);
        int* erow = edges + (size_t)row * CAP;
        int run = 0;
#pragma unroll 8
        for (int it = 0; it < NN / 4 / 64; ++it) {        // 16 iterations
            const int4 a = arow[it * 64 + lane];
            const unsigned long long b0 = __ballot(a.x != 0);
            const unsigned long long b1 = __ballot(a.y != 0);
            const unsigned long long b2 = __ballot(a.z != 0);
            const unsigned long long b3 = __ballot(a.w != 0);
            int pos = run + mbcnt64(b0) + mbcnt64(b1) + mbcnt64(b2) + mbcnt64(b3);
            const int col0 = (it * 64 + lane) * 4;
            if (a.x) { if (pos < CAP) erow[pos] = col0;     ++pos; }
            if (a.y) { if (pos < CAP) erow[pos] = col0 + 1; ++pos; }
            if (a.z) { if (pos < CAP) erow[pos] = col0 + 2; ++pos; }
            if (a.w) { if (pos < CAP) erow[pos] = col0 + 3; ++pos; }
            run += __popcll(b0) + __popcll(b1) + __popcll(b2) + __popcll(b3);
        }
        if (lane == 0) counts[row] = run;
    }
}

// ---------------------------------------------------------------------------
// Stage 2: per-row softmax + gather from CSR. Block = row, wave = head.
// ---------------------------------------------------------------------------
__global__ __launch_bounds__(256) void gat_attn(
    const int* __restrict__ counts, const int* __restrict__ edges,
    const float* __restrict__ h_prime, const float* __restrict__ src,
    const float* __restrict__ dst, const float* __restrict__ bias,
    float* __restrict__ out)
{
    const int i    = blockIdx.x;
    const int t    = threadIdx.x;
    const int wave = t >> 6, lane = t & 63;

    __shared__ int   idx_l[CAP];
    __shared__ float sc[NH][CAP];
    __shared__ float inv_sum[NH];

    const int count = min(counts[i], CAP);

    if (t < count) {
        const int j = edges[(size_t)i * CAP + t];
        idx_l[t] = j;
#pragma unroll
        for (int hh = 0; hh < NH; ++hh) {
            float s = src[hh * NN + i] + dst[hh * NN + j];
            sc[hh][t] = (s >= 0.f) ? s : 0.2f * s;   // leaky_relu(0.2)
        }
    }
    __syncthreads();

    {
        const int hh = wave;
        float m = -3.4e38f;
        for (int p = lane; p < count; p += 64) m = fmaxf(m, sc[hh][p]);
#pragma unroll
        for (int off = 32; off >= 1; off >>= 1) m = fmaxf(m, __shfl_xor(m, off, 64));
        float e = 0.f;
        for (int p = lane; p < count; p += 64) {
            float v = __expf(sc[hh][p] - m);
            sc[hh][p] = v;
            e += v;
        }
#pragma unroll
        for (int off = 32; off >= 1; off >>= 1) e += __shfl_xor(e, off, 64);
        if (lane == 0) inv_sum[hh] = 1.f / e;
    }
    __syncthreads();

    float acc = 0.f;
    const float* hp = h_prime + (size_t)(wave * NN) * FOUT + lane;
    for (int p = 0; p < count; ++p)
        acc = fmaf(sc[wave][p], hp[(size_t)idx_l[p] * FOUT], acc);
    out[(size_t)i * (NH * FOUT) + wave * FOUT + lane] = acc * inv_sum[wave] + bias[lane];
}

extern "C" void kernel_launch(void* const* d_in, const int* in_sizes, int n_in,
                              void* d_out, int out_size, void* d_ws, size_t ws_size,
                              hipStream_t stream) {
    const float* h     = (const float*)d_in[0];
    const int*   adj   = (const int*)d_in[1];
    const float* w     = (const float*)d_in[2];
    const float* a_src = (const float*)d_in[3];
    const float* a_dst = (const float*)d_in[4];
    const float* bias  = (const float*)d_in[5];
    float* out = (float*)d_out;

    float* wsf     = (float*)d_ws;
    float* h_prime = wsf;                        // NH*NN*FOUT floats = 4 MB
    float* src     = h_prime + NH * NN * FOUT;   // NH*NN
    float* dst     = src + NH * NN;              // NH*NN
    int*   counts  = (int*)(dst + NH * NN);      // NN ints
    int*   edges   = counts + NN;                // NN*CAP ints = 2 MB

    gat_stage1<<<HPB + SCB, 256, 0, stream>>>(h, adj, w, a_src, a_dst,
                                              h_prime, src, dst, counts, edges);
    gat_attn<<<NN, 256, 0, stream>>>(counts, edges, h_prime, src, dst, bias, out);
}

// Round 5
// 43.891 us; speedup vs baseline: 1.9780x; 1.0640x over previous
//
#include <hip/hip_runtime.h>

#define NN 4096
#define FIN 256
#define FOUT 64
#define NH 4
#define CAP 128    // max edges/row; Binomial(4096,0.01) mean 42, P(>127) ~ 1e-30
#define HPB 512    // hprime blocks: 8 nodes x 4 heads each
#define SCB 1024   // scan blocks: 4 rows each (one wave per row)

// popcount of mask restricted to lanes strictly below mine
__device__ __forceinline__ int mbcnt64(unsigned long long m) {
    return __builtin_amdgcn_mbcnt_hi((unsigned)(m >> 32),
           __builtin_amdgcn_mbcnt_lo((unsigned)m, 0));
}

// ---------------------------------------------------------------------------
// Stage 1 (fused, independent work split by blockIdx):
//   blocks [0, HPB):      h_prime GEMM + src/dst logits (8 nodes, wave = head)
//   blocks [HPB, +SCB):   adjacency scan -> CSR, load/compute/store decoupled
// ---------------------------------------------------------------------------
__global__ __launch_bounds__(256) void gat_stage1(
    const float* __restrict__ h, const int* __restrict__ adj,
    const float* __restrict__ w, const float* __restrict__ a_src,
    const float* __restrict__ a_dst,
    float* __restrict__ h_prime, float* __restrict__ src, float* __restrict__ dst,
    int* __restrict__ counts, int* __restrict__ edges)
{
    const int b    = blockIdx.x;
    const int t    = threadIdx.x;
    const int lane = t & 63;

    if (b < HPB) {
        // ---------------- h' part: 8 nodes, wave = head ----------------
        const int n0 = b * 8;
        const int hh = t >> 6;
        const int o  = lane;

        __shared__ float hs[8 * FIN];   // 8 KB
        for (int idx = t; idx < 8 * FIN / 4; idx += 256)
            ((float4*)hs)[idx] = ((const float4*)(h + (size_t)n0 * FIN))[idx];
        __syncthreads();

        const float* wp = w + hh * FIN * FOUT + o;   // coalesced over o
        float acc[8] = {0.f, 0.f, 0.f, 0.f, 0.f, 0.f, 0.f, 0.f};

#pragma unroll 4
        for (int f = 0; f < FIN; f += 4) {
            const float w0 = wp[(f + 0) * FOUT];
            const float w1 = wp[(f + 1) * FOUT];
            const float w2 = wp[(f + 2) * FOUT];
            const float w3 = wp[(f + 3) * FOUT];
#pragma unroll
            for (int n = 0; n < 8; ++n) {
                float4 hv = *(const float4*)&hs[n * FIN + f];  // broadcast
                acc[n] = fmaf(hv.x, w0, acc[n]);
                acc[n] = fmaf(hv.y, w1, acc[n]);
                acc[n] = fmaf(hv.z, w2, acc[n]);
                acc[n] = fmaf(hv.w, w3, acc[n]);
            }
        }

        const float as = a_src[hh * FOUT + o];
        const float ad = a_dst[hh * FOUT + o];
#pragma unroll
        for (int n = 0; n < 8; ++n) {
            h_prime[(size_t)(hh * NN + n0 + n) * FOUT + o] = acc[n];
            float vs = acc[n] * as;
            float vd = acc[n] * ad;
#pragma unroll
            for (int off = 32; off >= 1; off >>= 1) {
                vs += __shfl_xor(vs, off, 64);
                vd += __shfl_xor(vd, off, 64);
            }
            if (o == 0) {
                src[hh * NN + n0 + n] = vs;
                dst[hh * NN + n0 + n] = vd;
            }
        }
    } else {
        // ------------- scan part: one wave owns one row, 3 phases -------------
        const int row = (b - HPB) * 4 + (t >> 6);
        const int4* arow = (const int4*)(adj + (size_t)row * NN);

        // Phase A: issue all 16 row loads back-to-back (4 KB in flight,
        // no intervening vmem ops -> progressive vmcnt drain)
        int4 buf[16];
#pragma unroll
        for (int it = 0; it < 16; ++it)
            buf[it] = arow[it * 64 + lane];

        // Phase B: ballots -> per-iteration write positions (pure VALU/SALU)
        int pos[16];
        int run = 0;
#pragma unroll
        for (int it = 0; it < 16; ++it) {
            const unsigned long long b0 = __ballot(buf[it].x != 0);
            const unsigned long long b1 = __ballot(buf[it].y != 0);
            const unsigned long long b2 = __ballot(buf[it].z != 0);
            const unsigned long long b3 = __ballot(buf[it].w != 0);
            pos[it] = run + mbcnt64(b0) + mbcnt64(b1) + mbcnt64(b2) + mbcnt64(b3);
            run += __popcll(b0) + __popcll(b1) + __popcll(b2) + __popcll(b3);
        }

        // Phase C: all scatter stores (stores never gate loads)
        int* erow = edges + (size_t)row * CAP;
#pragma unroll
        for (int it = 0; it < 16; ++it) {
            int p = pos[it];
            const int col0 = (it * 64 + lane) * 4;
            if (buf[it].x) { if (p < CAP) erow[p] = col0;     ++p; }
            if (buf[it].y) { if (p < CAP) erow[p] = col0 + 1; ++p; }
            if (buf[it].z) { if (p < CAP) erow[p] = col0 + 2; ++p; }
            if (buf[it].w) { if (p < CAP) erow[p] = col0 + 3; ++p; }
        }
        if (lane == 0) counts[row] = run;
    }
}

// ---------------------------------------------------------------------------
// Stage 2: per-row softmax + gather from CSR. Block = row, wave = head.
// ---------------------------------------------------------------------------
__global__ __launch_bounds__(256) void gat_attn(
    const int* __restrict__ counts, const int* __restrict__ edges,
    const float* __restrict__ h_prime, const float* __restrict__ src,
    const float* __restrict__ dst, const float* __restrict__ bias,
    float* __restrict__ out)
{
    const int i    = blockIdx.x;
    const int t    = threadIdx.x;
    const int wave = t >> 6, lane = t & 63;

    __shared__ int   idx_l[CAP];
    __shared__ float sc[NH][CAP];
    __shared__ float inv_sum[NH];

    const int count = min(counts[i], CAP);

    if (t < count) {
        const int j = edges[(size_t)i * CAP + t];
        idx_l[t] = j;
#pragma unroll
        for (int hh = 0; hh < NH; ++hh) {
            float s = src[hh * NN + i] + dst[hh * NN + j];
            sc[hh][t] = (s >= 0.f) ? s : 0.2f * s;   // leaky_relu(0.2)
        }
    }
    __syncthreads();

    {
        const int hh = wave;
        float m = -3.4e38f;
        for (int p = lane; p < count; p += 64) m = fmaxf(m, sc[hh][p]);
#pragma unroll
        for (int off = 32; off >= 1; off >>= 1) m = fmaxf(m, __shfl_xor(m, off, 64));
        float e = 0.f;
        for (int p = lane; p < count; p += 64) {
            float v = __expf(sc[hh][p] - m);
            sc[hh][p] = v;
            e += v;
        }
#pragma unroll
        for (int off = 32; off >= 1; off >>= 1) e += __shfl_xor(e, off, 64);
        if (lane == 0) inv_sum[hh] = 1.f / e;
    }
    __syncthreads();

    float acc = 0.f;
    const float* hp = h_prime + (size_t)(wave * NN) * FOUT + lane;
    for (int p = 0; p < count; ++p)
        acc = fmaf(sc[wave][p], hp[(size_t)idx_l[p] * FOUT], acc);
    out[(size_t)i * (NH * FOUT) + wave * FOUT + lane] = acc * inv_sum[wave] + bias[lane];
}

extern "C" void kernel_launch(void* const* d_in, const int* in_sizes, int n_in,
                              void* d_out, int out_size, void* d_ws, size_t ws_size,
                              hipStream_t stream) {
    const float* h     = (const float*)d_in[0];
    const int*   adj   = (const int*)d_in[1];
    const float* w     = (const float*)d_in[2];
    const float* a_src = (const float*)d_in[3];
    const float* a_dst = (const float*)d_in[4];
    const float* bias  = (const float*)d_in[5];
    float* out = (float*)d_out;

    float* wsf     = (float*)d_ws;
    float* h_prime = wsf;                        // NH*NN*FOUT floats = 4 MB
    float* src     = h_prime + NH * NN * FOUT;   // NH*NN
    float* dst     = src + NH * NN;              // NH*NN
    int*   counts  = (int*)(dst + NH * NN);      // NN ints
    int*   edges   = counts + NN;                // NN*CAP ints = 2 MB

    gat_stage1<<<HPB + SCB, 256, 0, stream>>>(h, adj, w, a_src, a_dst,
                                              h_prime, src, dst, counts, edges);
    gat_attn<<<NN, 256, 0, stream>>>(counts, edges, h_prime, src, dst, bias, out);
}